// Round 4
// baseline (5337.490 us; speedup 1.0000x reference)
//
#include <hip/hip_runtime.h>

#define F 128

__global__ void spmm_coo_atomic(const int* __restrict__ rows,
                                const int* __restrict__ cols,
                                const float* __restrict__ vals,
                                const float* __restrict__ x,
                                float* __restrict__ out,
                                int nnz, int n_rows) {
    int t = blockIdx.x * blockDim.x + threadIdx.x;
    int e = t >> 5;          // 32 threads per edge
    int g = t & 31;          // feature group: 4 floats each -> 128 features
    if (e >= nnz) return;

    int r = rows[e];
    int c = cols[e];
    float v = vals[e];
    // Defensive: never fault even if index layout assumptions are wrong.
    if ((unsigned)r >= (unsigned)n_rows || (unsigned)c >= (unsigned)n_rows) return;

    const float4 xv = *reinterpret_cast<const float4*>(x + (long long)c * F + g * 4);
    float* o = out + (long long)r * F + g * 4;
    atomicAdd(o + 0, v * xv.x);
    atomicAdd(o + 1, v * xv.y);
    atomicAdd(o + 2, v * xv.z);
    atomicAdd(o + 3, v * xv.w);
}

extern "C" void kernel_launch(void* const* d_in, const int* in_sizes, int n_in,
                              void* d_out, int out_size, void* d_ws, size_t ws_size,
                              hipStream_t stream) {
    const float* x = (const float*)d_in[0];
    const int* A_ind = (const int*)d_in[1];
    const float* A_val = (const float*)d_in[2];
    float* out = (float*)d_out;

    const int nnz = in_sizes[2];            // A_val element count
    const int n_rows = out_size / F;        // N (=100000)
    const int* rows = A_ind;                // A_ind[0, :]
    const int* cols = A_ind + nnz;          // A_ind[1, :]

    // Zero the output (harness poisons it with 0xAA).
    hipMemsetAsync(d_out, 0, (size_t)out_size * sizeof(float), stream);

    const int threads_per_edge = 32;
    const long long total_threads = (long long)nnz * threads_per_edge;
    const int block = 256;
    const int grid = (int)((total_threads + block - 1) / block);
    spmm_coo_atomic<<<grid, block, 0, stream>>>(rows, cols, A_val, x, out, nnz, n_rows);
}

// Round 5
// 621.400 us; speedup vs baseline: 8.5895x; 8.5895x over previous
//
#include <hip/hip_runtime.h>

#define F 128
#define SCAN_CHUNK 1024
#define SCAN_T 256

// ---------------- fallback: atomic COO (round-4 proven) ----------------
__global__ void spmm_coo_atomic(const int* __restrict__ rows,
                                const int* __restrict__ cols,
                                const float* __restrict__ vals,
                                const float* __restrict__ x,
                                float* __restrict__ out,
                                int nnz, int n_rows) {
    int t = blockIdx.x * blockDim.x + threadIdx.x;
    int e = t >> 5;
    int g = t & 31;
    if (e >= nnz) return;
    int r = rows[e];
    int c = cols[e];
    float v = vals[e];
    if ((unsigned)r >= (unsigned)n_rows || (unsigned)c >= (unsigned)n_rows) return;
    const float4 xv = *reinterpret_cast<const float4*>(x + (size_t)c * F + g * 4);
    float* o = out + (size_t)r * F + g * 4;
    atomicAdd(o + 0, v * xv.x);
    atomicAdd(o + 1, v * xv.y);
    atomicAdd(o + 2, v * xv.z);
    atomicAdd(o + 3, v * xv.w);
}

// ---------------- CSR build ----------------
__global__ void k_histo(const int* __restrict__ rows, int* __restrict__ counts, int nnz) {
    int e = blockIdx.x * blockDim.x + threadIdx.x;
    if (e < nnz) atomicAdd(&counts[rows[e]], 1);
}

__global__ void k_scan1(const int* __restrict__ counts, int* __restrict__ offs,
                        int* __restrict__ blocksums, int n) {
    __shared__ int s[SCAN_T];
    int tid = threadIdx.x;
    int base = blockIdx.x * SCAN_CHUNK + tid * 4;
    int v[4];
#pragma unroll
    for (int k = 0; k < 4; ++k) {
        int i = base + k;
        v[k] = (i < n) ? counts[i] : 0;
    }
    int tsum = v[0] + v[1] + v[2] + v[3];
    s[tid] = tsum;
    __syncthreads();
    for (int off = 1; off < SCAN_T; off <<= 1) {
        int t = (tid >= off) ? s[tid - off] : 0;
        __syncthreads();
        s[tid] += t;
        __syncthreads();
    }
    int run = s[tid] - tsum;  // exclusive prefix of this thread
#pragma unroll
    for (int k = 0; k < 4; ++k) {
        int i = base + k;
        if (i < n) offs[i] = run;
        run += v[k];
    }
    if (tid == SCAN_T - 1) blocksums[blockIdx.x] = s[SCAN_T - 1];
}

__global__ void k_scan2(int* __restrict__ blocksums, int nb) {
    __shared__ int s[SCAN_T];
    int tid = threadIdx.x;
    int v = (tid < nb) ? blocksums[tid] : 0;
    s[tid] = v;
    __syncthreads();
    for (int off = 1; off < SCAN_T; off <<= 1) {
        int t = (tid >= off) ? s[tid - off] : 0;
        __syncthreads();
        s[tid] += t;
        __syncthreads();
    }
    if (tid < nb) blocksums[tid] = s[tid] - v;  // exclusive
}

__global__ void k_scan3(int* __restrict__ offs, const int* __restrict__ blocksums,
                        int* __restrict__ cursor, int n, int nnz_total) {
    int base = blockIdx.x * SCAN_CHUNK + threadIdx.x * 4;
    int add = blocksums[blockIdx.x];
#pragma unroll
    for (int k = 0; k < 4; ++k) {
        int idx = base + k;
        if (idx < n) {
            int o = offs[idx] + add;
            offs[idx] = o;
            cursor[idx] = o;
        }
    }
    if (blockIdx.x == 0 && threadIdx.x == 0) offs[n] = nnz_total;
}

__global__ void k_scatter(const int* __restrict__ rows, const int* __restrict__ cols,
                          const float* __restrict__ vals, int* __restrict__ cursor,
                          int* __restrict__ col_s, float* __restrict__ val_s, int nnz) {
    int e = blockIdx.x * blockDim.x + threadIdx.x;
    if (e >= nnz) return;
    int r = rows[e];
    int pos = atomicAdd(&cursor[r], 1);
    col_s[pos] = cols[e];
    val_s[pos] = vals[e];
}

// ---------------- CSR SpMM: one wave per output row ----------------
__global__ void k_spmm_csr(const int* __restrict__ offs, const int* __restrict__ col_s,
                           const float* __restrict__ val_s, const float* __restrict__ x,
                           float* __restrict__ out, int n_rows) {
    int gid = blockIdx.x * blockDim.x + threadIdx.x;
    int row = gid >> 6;          // one 64-lane wave per row
    int lane = threadIdx.x & 63;
    if (row >= n_rows) return;
    int beg = offs[row], end = offs[row + 1];
    float2 acc = make_float2(0.f, 0.f);
    for (int i = beg; i < end; i += 64) {
        int j = i + lane;
        int c = 0;
        float v = 0.f;
        if (j < end) { c = col_s[j]; v = val_s[j]; }
        int m = min(64, end - i);   // wave-uniform
        for (int k = 0; k < m; ++k) {
            int ck = __shfl(c, k);
            float vk = __shfl(v, k);
            const float2 xv = *reinterpret_cast<const float2*>(x + (size_t)ck * F + lane * 2);
            acc.x += vk * xv.x;
            acc.y += vk * xv.y;
        }
    }
    *reinterpret_cast<float2*>(out + (size_t)row * F + lane * 2) = acc;
}

extern "C" void kernel_launch(void* const* d_in, const int* in_sizes, int n_in,
                              void* d_out, int out_size, void* d_ws, size_t ws_size,
                              hipStream_t stream) {
    const float* x = (const float*)d_in[0];
    const int* A_ind = (const int*)d_in[1];
    const float* A_val = (const float*)d_in[2];
    float* out = (float*)d_out;

    const int nnz = in_sizes[2];
    const int n = out_size / F;  // 100000
    const int* rows = A_ind;
    const int* cols = A_ind + nnz;

    const int nb = (n + SCAN_CHUNK - 1) / SCAN_CHUNK;
    const size_t need = ((size_t)n + (size_t)(n + 1) + 256 + (size_t)n) * 4
                      + (size_t)nnz * 8;

    if (nb > SCAN_T || ws_size < need) {
        // Fallback: proven atomic path.
        hipMemsetAsync(d_out, 0, (size_t)out_size * sizeof(float), stream);
        const long long total = (long long)nnz * 32;
        spmm_coo_atomic<<<(int)((total + 255) / 256), 256, 0, stream>>>(
            rows, cols, A_val, x, out, nnz, n);
        return;
    }

    char* w = (char*)d_ws;
    int* counts = (int*)w;      w += (size_t)n * 4;
    int* offs = (int*)w;        w += (size_t)(n + 1) * 4;
    int* blocksums = (int*)w;   w += 256 * 4;
    int* cursor = (int*)w;      w += (size_t)n * 4;
    int* col_s = (int*)w;       w += (size_t)nnz * 4;
    float* val_s = (float*)w;

    hipMemsetAsync(counts, 0, (size_t)n * 4, stream);
    k_histo<<<(nnz + 255) / 256, 256, 0, stream>>>(rows, counts, nnz);
    k_scan1<<<nb, SCAN_T, 0, stream>>>(counts, offs, blocksums, n);
    k_scan2<<<1, SCAN_T, 0, stream>>>(blocksums, nb);
    k_scan3<<<nb, SCAN_T, 0, stream>>>(offs, blocksums, cursor, n, nnz);
    k_scatter<<<(nnz + 255) / 256, 256, 0, stream>>>(rows, cols, A_val, cursor,
                                                     col_s, val_s, nnz);
    // Writes every output row exactly once (zeros for empty rows) -> no out memset.
    k_spmm_csr<<<(n * 64 + 255) / 256, 256, 0, stream>>>(offs, col_s, val_s, x, out, n);
}

// Round 6
// 614.867 us; speedup vs baseline: 8.6807x; 1.0106x over previous
//
#include <hip/hip_runtime.h>

#define F 128
#define SCAN_CHUNK 1024
#define SCAN_T 256

// ---------------- fallback: atomic COO (round-4 proven) ----------------
__global__ void spmm_coo_atomic(const int* __restrict__ rows,
                                const int* __restrict__ cols,
                                const float* __restrict__ vals,
                                const float* __restrict__ x,
                                float* __restrict__ out,
                                int nnz, int n_rows) {
    int t = blockIdx.x * blockDim.x + threadIdx.x;
    int e = t >> 5;
    int g = t & 31;
    if (e >= nnz) return;
    int r = rows[e];
    int c = cols[e];
    float v = vals[e];
    if ((unsigned)r >= (unsigned)n_rows || (unsigned)c >= (unsigned)n_rows) return;
    const float4 xv = *reinterpret_cast<const float4*>(x + (size_t)c * F + g * 4);
    float* o = out + (size_t)r * F + g * 4;
    atomicAdd(o + 0, v * xv.x);
    atomicAdd(o + 1, v * xv.y);
    atomicAdd(o + 2, v * xv.z);
    atomicAdd(o + 3, v * xv.w);
}

// ---------------- CSR build ----------------
__global__ void k_histo(const int* __restrict__ rows, int* __restrict__ counts, int nnz) {
    int e = blockIdx.x * blockDim.x + threadIdx.x;
    if (e < nnz) atomicAdd(&counts[rows[e]], 1);
}

__global__ void k_scan1(const int* __restrict__ counts, int* __restrict__ offs,
                        int* __restrict__ blocksums, int n) {
    __shared__ int s[SCAN_T];
    int tid = threadIdx.x;
    int base = blockIdx.x * SCAN_CHUNK + tid * 4;
    int v[4];
#pragma unroll
    for (int k = 0; k < 4; ++k) {
        int i = base + k;
        v[k] = (i < n) ? counts[i] : 0;
    }
    int tsum = v[0] + v[1] + v[2] + v[3];
    s[tid] = tsum;
    __syncthreads();
    for (int off = 1; off < SCAN_T; off <<= 1) {
        int t = (tid >= off) ? s[tid - off] : 0;
        __syncthreads();
        s[tid] += t;
        __syncthreads();
    }
    int run = s[tid] - tsum;  // exclusive prefix of this thread
#pragma unroll
    for (int k = 0; k < 4; ++k) {
        int i = base + k;
        if (i < n) offs[i] = run;
        run += v[k];
    }
    if (tid == SCAN_T - 1) blocksums[blockIdx.x] = s[SCAN_T - 1];
}

__global__ void k_scan2(int* __restrict__ blocksums, int nb) {
    __shared__ int s[SCAN_T];
    int tid = threadIdx.x;
    int v = (tid < nb) ? blocksums[tid] : 0;
    s[tid] = v;
    __syncthreads();
    for (int off = 1; off < SCAN_T; off <<= 1) {
        int t = (tid >= off) ? s[tid - off] : 0;
        __syncthreads();
        s[tid] += t;
        __syncthreads();
    }
    if (tid < nb) blocksums[tid] = s[tid] - v;  // exclusive
}

__global__ void k_scan3(int* __restrict__ offs, const int* __restrict__ blocksums,
                        int* __restrict__ cursor, int n, int nnz_total) {
    int base = blockIdx.x * SCAN_CHUNK + threadIdx.x * 4;
    int add = blocksums[blockIdx.x];
#pragma unroll
    for (int k = 0; k < 4; ++k) {
        int idx = base + k;
        if (idx < n) {
            int o = offs[idx] + add;
            offs[idx] = o;
            cursor[idx] = o;
        }
    }
    if (blockIdx.x == 0 && threadIdx.x == 0) offs[n] = nnz_total;
}

// Packed scatter: one 8B store per edge (col, val) instead of two 4B stores.
__global__ void k_scatter(const int* __restrict__ rows, const int* __restrict__ cols,
                          const float* __restrict__ vals, int* __restrict__ cursor,
                          int2* __restrict__ pair_s, int nnz) {
    int e = blockIdx.x * blockDim.x + threadIdx.x;
    if (e >= nnz) return;
    int r = rows[e];
    int pos = atomicAdd(&cursor[r], 1);
    pair_s[pos] = make_int2(cols[e], __float_as_int(vals[e]));
}

// ---------------- CSR SpMM: one wave per row, 2 edges per inner iteration ----
__global__ void k_spmm_csr(const int* __restrict__ offs, const int2* __restrict__ pair_s,
                           const float* __restrict__ x, float* __restrict__ out,
                           int n_rows) {
    int gid = blockIdx.x * blockDim.x + threadIdx.x;
    int row = gid >> 6;          // one 64-lane wave per row
    int lane = threadIdx.x & 63;
    if (row >= n_rows) return;
    int half = lane >> 5;        // which of the 2 concurrent edges this lane serves
    int fl = lane & 31;          // feature-lane: owns 4 floats
    int beg = offs[row], end = offs[row + 1];

    float4 acc = make_float4(0.f, 0.f, 0.f, 0.f);
    for (int i = beg; i < end; i += 64) {
        int j = i + lane;
        int c = 0;
        float v = 0.f;
        if (j < end) {
            int2 pr = pair_s[j];
            c = pr.x;
            v = __int_as_float(pr.y);
        }
        int m = min(64, end - i);   // wave-uniform
        for (int k = 0; k < m; k += 2) {
            int kk = k + half;                 // lanes<32: edge k, lanes>=32: edge k+1
            int ck = __shfl(c, kk);            // out-of-range kk reads (0, 0.f) — safe
            float vk = __shfl(v, kk);
            const float4 xv = *reinterpret_cast<const float4*>(x + (size_t)ck * F + fl * 4);
            acc.x += vk * xv.x;
            acc.y += vk * xv.y;
            acc.z += vk * xv.z;
            acc.w += vk * xv.w;
        }
    }
    // Merge the two halves: lane fl += lane fl+32.
    acc.x += __shfl_xor(acc.x, 32);
    acc.y += __shfl_xor(acc.y, 32);
    acc.z += __shfl_xor(acc.z, 32);
    acc.w += __shfl_xor(acc.w, 32);
    if (half == 0) {
        *reinterpret_cast<float4*>(out + (size_t)row * F + fl * 4) = acc;
    }
}

extern "C" void kernel_launch(void* const* d_in, const int* in_sizes, int n_in,
                              void* d_out, int out_size, void* d_ws, size_t ws_size,
                              hipStream_t stream) {
    const float* x = (const float*)d_in[0];
    const int* A_ind = (const int*)d_in[1];
    const float* A_val = (const float*)d_in[2];
    float* out = (float*)d_out;

    const int nnz = in_sizes[2];
    const int n = out_size / F;  // 100000
    const int* rows = A_ind;
    const int* cols = A_ind + nnz;

    const int nb = (n + SCAN_CHUNK - 1) / SCAN_CHUNK;
    const size_t need = ((size_t)n + (size_t)(n + 1) + 256 + (size_t)n) * 4
                      + (size_t)nnz * 8;

    if (nb > SCAN_T || ws_size < need) {
        // Fallback: proven atomic path.
        hipMemsetAsync(d_out, 0, (size_t)out_size * sizeof(float), stream);
        const long long total = (long long)nnz * 32;
        spmm_coo_atomic<<<(int)((total + 255) / 256), 256, 0, stream>>>(
            rows, cols, A_val, x, out, nnz, n);
        return;
    }

    char* w = (char*)d_ws;
    int* counts = (int*)w;      w += (size_t)n * 4;
    int* offs = (int*)w;        w += (size_t)(n + 1) * 4;
    int* blocksums = (int*)w;   w += 256 * 4;
    int* cursor = (int*)w;      w += (size_t)n * 4;
    int2* pair_s = (int2*)w;

    hipMemsetAsync(counts, 0, (size_t)n * 4, stream);
    k_histo<<<(nnz + 255) / 256, 256, 0, stream>>>(rows, counts, nnz);
    k_scan1<<<nb, SCAN_T, 0, stream>>>(counts, offs, blocksums, n);
    k_scan2<<<1, SCAN_T, 0, stream>>>(blocksums, nb);
    k_scan3<<<nb, SCAN_T, 0, stream>>>(offs, blocksums, cursor, n, nnz);
    k_scatter<<<(nnz + 255) / 256, 256, 0, stream>>>(rows, cols, A_val, cursor,
                                                     pair_s, nnz);
    // Writes every output row exactly once (zeros for empty rows) -> no out memset.
    k_spmm_csr<<<(n * 64 + 255) / 256, 256, 0, stream>>>(offs, pair_s, x, out, n);
}